// Round 2
// baseline (3837.123 us; speedup 1.0000x reference)
//
#include <hip/hip_runtime.h>

// EncoderRNN: bidirectional GRU, T=1024, B=64, H=256, V=32000, fp32.
// Round 8 (post-mortem of R7 regression):
//  - xg_gemm: reverted to the r0 LDS-staged version (R7 direct-L2 loads
//    regressed 192->415 us from register-pressure serialization). Only
//    change: bhh for the r,z gates is folded into the bias here.
//  - gru_scan restructured to shorten the serial per-step chain:
//      * gate-grouped tile ownership: wave wv computes r,z,n rows for
//        j in [32wv,32wv+32) -> MFMA results are consumed by the SAME
//        wave. The res redistribution is a same-wave LDS bounce with no
//        barrier (lgkmcnt only); epilogue stays 1 cell/lane (64 lanes).
//      * ONE barrier per step (hbf double-buffered by parity) instead of 2.
//      * sigmoid/tanh via v_rcp_f32 (__builtin_amdgcn_rcpf) instead of
//        3 IEEE division sequences on the chain.
//      * MFMA accumulation split into two 4-deep chains (kc even/odd).
//      * out written with atomicAdd (2 addends, commutative -> bit-identical);
//        removes the oprev load path entirely.
//
// ws layout (float offsets):
//   hcar  : 0        [dir][b][j] 2*64*256 = 32768
//   pA    : 32768    scan Whh bf16 A-frags [dir][tile48][kc8][lane64][jj8] = 2*196608 ush
//   pWihB : 229376   xg Wih bf16 B-frags  [dir][kc8][nt48][lane64][jj8]   = 2*196608 ush
//   embB  : 425984   bf16 embedding table, 32000*256 = 8192000 ush
//   xg    : 4521984  two chunk buffers of Tc*64*768 floats each (f then b)

typedef __attribute__((ext_vector_type(8))) short short8;    // 8 bf16 (4 VGPRs)
typedef __attribute__((ext_vector_type(4))) float floatx4;   // 4 fp32

__device__ __forceinline__ float rcp_(float x) { return __builtin_amdgcn_rcpf(x); }
__device__ __forceinline__ float sigmoid_(float x) { return rcp_(1.0f + __expf(-x)); }
__device__ __forceinline__ float tanh_(float x)    { return 1.0f - 2.0f * rcp_(1.0f + __expf(2.0f * x)); }
__device__ __forceinline__ unsigned short f2bf(float f) {     // RNE fp32->bf16
  unsigned int u = __float_as_uint(f);
  return (unsigned short)((u + 0x7fffu + ((u >> 16) & 1u)) >> 16);
}

// LDS-only barrier: waits ds ops, leaves global loads/stores/atomics in flight.
__device__ __forceinline__ void ldsbar() {
  asm volatile("s_waitcnt lgkmcnt(0)" ::: "memory");
  __builtin_amdgcn_s_barrier();
  asm volatile("" ::: "memory");
}

// ---------------- prep kernels ----------------

__global__ __launch_bounds__(256) void prep_embB(
    const float* __restrict__ emb, unsigned short* __restrict__ embB) {
  int i4 = blockIdx.x * 256 + threadIdx.x;       // 0 .. 2047999 (float4 units)
  float4 v = ((const float4*)emb)[i4];
  ushort4 o;
  o.x = f2bf(v.x); o.y = f2bf(v.y); o.z = f2bf(v.z); o.w = f2bf(v.w);
  ((ushort4*)embB)[i4] = o;
}

// Wih -> bf16 MFMA B-frags. [dir][kc][nt][lane][jj]: B[k][n]=Wih[n][k],
// n = nt*16 + (lane&15), k = kc*32 + (lane>>4)*8 + jj.
__global__ __launch_bounds__(256) void prep_packB(
    const float* __restrict__ wf, const float* __restrict__ wb,
    unsigned short* __restrict__ oB) {
  int idx = blockIdx.x * 256 + threadIdx.x;      // 0 .. 2*196608-1
  int d = idx >= 196608;
  int o = idx - d * 196608;
  int jj   = o & 7;
  int lane = (o >> 3) & 63;
  int rest = o >> 9;                             // 0..383 = kc*48 + nt
  int nt   = rest % 48;
  int kc   = rest / 48;
  int n = nt * 16 + (lane & 15);
  int k = kc * 32 + ((lane >> 4) << 3) + jj;
  const float* w = d ? wb : wf;
  oB[idx] = f2bf(w[n * 256 + k]);
}

// Whh -> bf16 MFMA A-frags.
// pA[dir][tile(48)][kc(8)][lane(64)][jj(8)]: row = tile*16 + (lane&15),
// k = kc*32 + (lane>>4)*8 + jj.
__global__ __launch_bounds__(256) void prep_packA(
    const float* __restrict__ wf, const float* __restrict__ wb,
    unsigned short* __restrict__ oA) {
  int idx = blockIdx.x * 256 + threadIdx.x;      // 0 .. 2*196608-1
  int d = idx >= 196608;
  int o = idx - d * 196608;
  int jj   = o & 7;
  int lane = (o >> 3) & 63;
  int kc   = (o >> 9) & 7;
  int tl   = o >> 12;                            // 0..47
  int row  = tl * 16 + (lane & 15);
  int k    = kc * 32 + ((lane >> 4) << 3) + jj;
  const float* w = d ? wb : wf;
  oA[idx] = f2bf(w[row * 256 + k]);
}

// ---------------- xg GEMM (bf16 MFMA, LDS-staged B — r0 version) ----------
// Block = one (sx, dir): 256 thr / 4 waves. Wave w -> m-tile w (batches
// 16w..16w+15), all 48 n-tiles. A gathered per-lane from embB; B staged
// per-kc in LDS (48 KB). Bias = bih + bhh for the r,z gates (folded here
// so the scan epilogue drops two adds from its serial chain).
__global__ __launch_bounds__(256) void xg_gemm(
    const int* __restrict__ seq,
    const unsigned short* __restrict__ embB,
    const unsigned short* __restrict__ pWihB,
    const float* __restrict__ bih_f, const float* __restrict__ bih_b,
    const float* __restrict__ bhh_f, const float* __restrict__ bhh_b,
    float* __restrict__ xg_f, float* __restrict__ xg_b,
    int base_f, int base_b) {
  const int tid  = threadIdx.x;
  const int lane = tid & 63;
  const int w    = tid >> 6;
  const int sx   = blockIdx.x;
  const int dir  = blockIdx.y;
  const int t    = (dir ? base_b : base_f) + sx;
  const int c    = lane & 15, qq = lane >> 4;

  const float* bih = dir ? bih_b : bih_f;
  const float* bhh = dir ? bhh_b : bhh_f;
  float* xgo = (dir ? xg_b : xg_f) + (size_t)sx * 64 * 768;

  // A-frags: token row for m = lane&15 of tile w; prefetch all 8 kc.
  const int tk = seq[t * 64 + w * 16 + c];
  const unsigned short* aptr = embB + (size_t)tk * 256 + qq * 8;
  short8 afr[8];
#pragma unroll
  for (int kc = 0; kc < 8; ++kc) afr[kc] = *(const short8*)(aptr + kc * 32);

  __shared__ __align__(16) float4 Bs4[3072];     // 48 KB: [nt48][lane64][jj8] bf16

  floatx4 acc[48];
#pragma unroll
  for (int nt = 0; nt < 48; ++nt) acc[nt] = (floatx4){0.f, 0.f, 0.f, 0.f};

  for (int kc = 0; kc < 8; ++kc) {
    __syncthreads();
    const float4* src = (const float4*)(pWihB + (size_t)dir * 196608 + kc * 24576);
#pragma unroll
    for (int i = 0; i < 12; ++i) Bs4[tid + i * 256] = src[tid + i * 256];
    __syncthreads();
    const short8* bsv = (const short8*)Bs4;
    short8 af = afr[kc];
#pragma unroll
    for (int nt = 0; nt < 48; ++nt)
      acc[nt] = __builtin_amdgcn_mfma_f32_16x16x32_bf16(af, bsv[nt * 64 + lane], acc[nt], 0, 0, 0);
  }

  // D: col = lane&15 (n within tile), row = qq*4+reg (m = batch within tile)
#pragma unroll
  for (int nt = 0; nt < 48; ++nt) {
    int n = nt * 16 + c;
    float bv = bih[n] + (n < 512 ? bhh[n] : 0.0f);   // fold bhh_r, bhh_z
#pragma unroll
    for (int r = 0; r < 4; ++r)
      xgo[(size_t)(w * 16 + qq * 4 + r) * 768 + n] = acc[nt][r] + bv;
  }
}

// ---------------- recurrent scan (fused in-wave epilogue, 1 barrier) ------
// Grid (32 pairs, 2 dirs) x 512 threads. Wave wv owns the r,z,n rows for
// j in [32wv, 32wv+32): tiles {g*16 + 2wv, g*16 + 2wv + 1 | g=0,1,2}.
// Per step: hbf[p](LDS) -> B-frags -> 48 MFMA/wave (two 4-deep chains)
// -> same-wave res bounce (no barrier) -> 1-cell/lane epilogue ->
// hbf[p^1] write + atomic out -> ONE barrier.
__global__ __launch_bounds__(512, 2) void gru_scan(
    const int* __restrict__ lens,
    const float* __restrict__ xg_f, const float* __restrict__ xg_b,
    const unsigned short* __restrict__ pA,
    const float* __restrict__ bhh_f, const float* __restrict__ bhh_b,
    float* __restrict__ out, float* __restrict__ hcar,
    int base_f, int base_b, int Tc, int is_last) {
  const int tid  = threadIdx.x;
  const int lane = tid & 63;
  const int wv   = tid >> 6;                     // 0..7
  const int qp   = blockIdx.x;                   // batch pair
  const int dir  = blockIdx.y;
  const int b0   = qp * 2;

  const float* xg  = dir ? xg_b : xg_f;
  const float* bhh = dir ? bhh_b : bhh_f;
  const int len0 = lens[b0], len1 = lens[b0 + 1];
  const int lenmax = len0 > len1 ? len0 : len1;
  const int base = dir ? base_b : base_f;

  // Resident A-fragments, gate-grouped: i = g*2+sub -> tile g*16 + 2wv + sub.
  short8 af[6][8];
  {
    const short8* pA8 = (const short8*)(pA + (size_t)dir * 196608);
#pragma unroll
    for (int i = 0; i < 6; ++i) {
      const int tl = (i >> 1) * 16 + wv * 2 + (i & 1);
#pragma unroll
      for (int kc = 0; kc < 8; ++kc)
        af[i][kc] = pA8[((tl * 8 + kc) << 6) + lane];
    }
  }

  __shared__ __align__(16) unsigned short hbf[2 * 576];  // [parity][b][288]
  __shared__ __align__(16) float res[1536];              // [wv][g][b][32]

  // Epilogue identity: each lane owns one cell (b = lane>>5, j = 32wv + jj).
  const int b  = lane >> 5;
  const int jj = lane & 31;
  const int j  = wv * 32 + jj;
  const int bb = b0 + b;
  const int blen = b ? len1 : len0;
  float hreg = hcar[dir * 16384 + bb * 256 + j];
  const float bhn = bhh[512 + j];
  hbf[b * 288 + j] = f2bf(hreg);                 // parity 0
  ldsbar();

  int s_lo, s_hi;
  if (dir == 0) { s_lo = 0; int e = lenmax - base; s_hi = e < 0 ? 0 : (e > Tc ? Tc : e); }
  else { int sk = base + Tc - lenmax; s_lo = sk < 0 ? 0 : (sk > Tc ? Tc : sk); s_hi = Tc; }

  const int nB = lane & 15, qq = lane >> 4;
  const bool bld = nB < 2;                       // 8 lanes/wave carry B data
  const unsigned short* hsrc0 = &hbf[nB * 288 + qq * 8];

  // Preload first step's xg operands (consumed after the MFMA phase).
  float xr = 0.f, xz = 0.f, xn = 0.f;
  if (s_lo < s_hi) {
    const int t0  = dir ? (base + (Tc - 1 - s_lo)) : (base + s_lo);
    const float* xrow = xg + ((size_t)(t0 - base) * 64 + bb) * 768;
    xr = xrow[j]; xz = xrow[256 + j]; xn = xrow[512 + j];
  }

  int p = 0;
  for (int s = s_lo; s < s_hi; ++s) {
    const int t  = dir ? (base + (Tc - 1 - s)) : (base + s);
    const bool act = t < blen;

    // Prefetch NEXT step's xg operands (consumed next iteration).
    const int sn = (s + 1 < s_hi) ? s + 1 : s;
    const int tn = dir ? (base + (Tc - 1 - sn)) : (base + sn);
    float xr2, xz2, xn2;
    {
      const float* xrow = xg + ((size_t)(tn - base) * 64 + bb) * 768;
      xr2 = xrow[j]; xz2 = xrow[256 + j]; xn2 = xrow[512 + j];
    }

    floatx4 accE[6], accO[6];
#pragma unroll
    for (int i = 0; i < 6; ++i) {
      accE[i] = (floatx4){0.f, 0.f, 0.f, 0.f};
      accO[i] = (floatx4){0.f, 0.f, 0.f, 0.f};
    }

    const unsigned short* hsrc = hsrc0 + p * 576;
#pragma unroll
    for (int kc = 0; kc < 8; kc += 2) {          // two independent 4-deep chains
      short8 bfrE = {0, 0, 0, 0, 0, 0, 0, 0};
      short8 bfrO = {0, 0, 0, 0, 0, 0, 0, 0};
      if (bld) {
        bfrE = *(const short8*)(hsrc + kc * 32);
        bfrO = *(const short8*)(hsrc + kc * 32 + 32);
      }
#pragma unroll
      for (int i = 0; i < 6; ++i)
        accE[i] = __builtin_amdgcn_mfma_f32_16x16x32_bf16(af[i][kc], bfrE, accE[i], 0, 0, 0);
#pragma unroll
      for (int i = 0; i < 6; ++i)
        accO[i] = __builtin_amdgcn_mfma_f32_16x16x32_bf16(af[i][kc + 1], bfrO, accO[i], 0, 0, 0);
    }

    // Same-wave res bounce: D col = lane&15 (batch), row = qq*4+reg.
    // res[wv][g][b][32]: write 4 consecutive j per lane, read 1 cell/lane.
    if (bld) {
#pragma unroll
      for (int i = 0; i < 6; ++i) {
        const int g = i >> 1, sub = i & 1;
        *(floatx4*)&res[(((wv * 3 + g) * 2 + nB) << 5) + sub * 16 + qq * 4] =
            accE[i] + accO[i];
      }
    }
    // Compiler orders the may-aliasing LDS ops and emits the lgkm wait; the
    // producer lanes are in this same wave, so no barrier is needed here.
    float ar = res[(((wv * 3 + 0) * 2 + b) << 5) + jj];
    float az = res[(((wv * 3 + 1) * 2 + b) << 5) + jj];
    float an = res[(((wv * 3 + 2) * 2 + b) << 5) + jj];

    // xr/xz already include bih + bhh (folded in xg_gemm); xn includes bih.
    float r  = sigmoid_(xr + ar);
    float z  = sigmoid_(xz + az);
    float nn = tanh_(xn + r * (an + bhn));
    float hn = z * (hreg - nn) + nn;
    if (act) hreg = hn;
    hbf[((p ^ 1) * 576) + b * 288 + j] = f2bf(hreg);
    if (act) atomicAdd(&out[((size_t)t * 64 + bb) * 256 + j], hn);
    ldsbar();                                    // the ONE barrier per step
    p ^= 1;

    xr = xr2; xz = xz2; xn = xn2;
  }

  hcar[dir * 16384 + bb * 256 + j] = hreg;
  if (is_last)
    out[(size_t)1024 * 64 * 256 + (size_t)dir * 16384 + bb * 256 + j] = hreg;
}

extern "C" void kernel_launch(void* const* d_in, const int* in_sizes, int n_in,
                              void* d_out, int out_size, void* d_ws, size_t ws_size,
                              hipStream_t stream) {
  const int*   seq   = (const int*)d_in[0];
  const int*   lens  = (const int*)d_in[1];
  const float* emb   = (const float*)d_in[2];
  const float* Wih_f = (const float*)d_in[3];
  const float* Whh_f = (const float*)d_in[4];
  const float* bih_f = (const float*)d_in[5];
  const float* bhh_f = (const float*)d_in[6];
  const float* Wih_b = (const float*)d_in[7];
  const float* Whh_b = (const float*)d_in[8];
  const float* bih_b = (const float*)d_in[9];
  const float* bhh_b = (const float*)d_in[10];
  float* out = (float*)d_out;
  float* ws  = (float*)d_ws;

  float*          hcar   = ws;
  unsigned short* pA     = (unsigned short*)(ws + 32768);
  unsigned short* pWihB  = (unsigned short*)(ws + 229376);
  unsigned short* embB   = (unsigned short*)(ws + 425984);
  float*          xgbase = ws + 4521984;

  // Largest Tc whose two xg chunk buffers fit in ws (C = 1024/Tc even).
  int Tc = 8;
  const int cands[7] = {512, 256, 128, 64, 32, 16, 8};
  for (int i = 0; i < 7; ++i) {
    size_t need = (4521984ull + 2ull * (size_t)cands[i] * 49152ull) * 4ull;
    if (need <= ws_size) { Tc = cands[i]; break; }
  }
  const int C = 1024 / Tc;
  float* xg_f = xgbase;
  float* xg_b = xgbase + (size_t)Tc * 49152;

  hipMemsetAsync(d_out, 0, (size_t)1024 * 64 * 256 * 4, stream);  // out accumulated via atomicAdd
  hipMemsetAsync(hcar, 0, 32768ull * 4ull, stream);               // initial h = 0
  prep_embB<<<dim3(8000), dim3(256), 0, stream>>>(emb, embB);
  prep_packB<<<dim3(1536), dim3(256), 0, stream>>>(Wih_f, Wih_b, pWihB);
  prep_packA<<<dim3(1536), dim3(256), 0, stream>>>(Whh_f, Whh_b, pA);

  for (int c = 0; c < C; ++c) {
    int base_f = c * Tc;
    int base_b = (C - 1 - c) * Tc;               // mirrored chunk for reverse scan
    xg_gemm<<<dim3(Tc, 2), dim3(256), 0, stream>>>(
        seq, embB, pWihB, bih_f, bih_b, bhh_f, bhh_b, xg_f, xg_b, base_f, base_b);
    gru_scan<<<dim3(32, 2), dim3(512), 0, stream>>>(
        lens, xg_f, xg_b, pA, bhh_f, bhh_b, out, hcar,
        base_f, base_b, Tc, (c == C - 1) ? 1 : 0);
  }
}

// Round 3
// 1688.075 us; speedup vs baseline: 2.2731x; 2.2731x over previous
//
#include <hip/hip_runtime.h>

// EncoderRNN: bidirectional GRU, T=1024, B=64, H=256, V=32000, fp32.
// Round 9 (post-mortem of R8: the 16.8M device-scope atomicAdds were the
// ~+0.9ms regression; one-barrier restructure unproven):
//  - gru_scan: full revert to the known-797us R4 structure (2 syncthreads,
//    wave-owns-6-tiles, res redistribution, prefetched oprev + plain store).
//    Kept only the safe R8 tweaks: rcp-based sigmoid/tanh, r/z bias folded
//    into xg, plus s_setprio(1) for the scan waves.
//  - NEW: heterogeneous fused launch. The scan uses only 64 of 256 CUs and
//    xg_gemm(c+1) depends only on the preps, so each launch runs
//    scan(chunk c) on blocks [0,64) and xg_gemm(chunk c+1) on blocks
//    [64, 64+2*Tc). xg chunks are double-buffered (4 buffers -> Tc=256).
//    Kernel-boundary ordering provides all dependencies; the serial ~400us
//    of xg work hides under the scan.
//
// ws layout (float offsets):
//   hcar  : 0        [dir][b][j] 2*64*256 = 32768
//   pA    : 32768    scan Whh bf16 A-frags [dir][tile48][kc8][lane64][jj8] = 2*196608 ush
//   pWihB : 229376   xg Wih bf16 B-frags  [dir][kc8][nt48][lane64][jj8]   = 2*196608 ush
//   embB  : 425984   bf16 embedding table, 32000*256 = 8192000 ush
//   xg    : 4521984  four chunk buffers of Tc*64*768 floats [parity][dir]

typedef __attribute__((ext_vector_type(8))) short short8;    // 8 bf16 (4 VGPRs)
typedef __attribute__((ext_vector_type(4))) float floatx4;   // 4 fp32

__device__ __forceinline__ float rcp_(float x) { return __builtin_amdgcn_rcpf(x); }
__device__ __forceinline__ float sigmoid_(float x) { return rcp_(1.0f + __expf(-x)); }
__device__ __forceinline__ float tanh_(float x)    { return 1.0f - 2.0f * rcp_(1.0f + __expf(2.0f * x)); }
__device__ __forceinline__ unsigned short f2bf(float f) {     // RNE fp32->bf16
  unsigned int u = __float_as_uint(f);
  return (unsigned short)((u + 0x7fffu + ((u >> 16) & 1u)) >> 16);
}

// ---------------- prep kernels ----------------

__global__ __launch_bounds__(256) void prep_embB(
    const float* __restrict__ emb, unsigned short* __restrict__ embB) {
  int i4 = blockIdx.x * 256 + threadIdx.x;       // 0 .. 2047999 (float4 units)
  float4 v = ((const float4*)emb)[i4];
  ushort4 o;
  o.x = f2bf(v.x); o.y = f2bf(v.y); o.z = f2bf(v.z); o.w = f2bf(v.w);
  ((ushort4*)embB)[i4] = o;
}

// Wih -> bf16 MFMA B-frags. [dir][kc][nt][lane][jj]: B[k][n]=Wih[n][k],
// n = nt*16 + (lane&15), k = kc*32 + (lane>>4)*8 + jj.
__global__ __launch_bounds__(256) void prep_packB(
    const float* __restrict__ wf, const float* __restrict__ wb,
    unsigned short* __restrict__ oB) {
  int idx = blockIdx.x * 256 + threadIdx.x;      // 0 .. 2*196608-1
  int d = idx >= 196608;
  int o = idx - d * 196608;
  int jj   = o & 7;
  int lane = (o >> 3) & 63;
  int rest = o >> 9;                             // 0..383 = kc*48 + nt
  int nt   = rest % 48;
  int kc   = rest / 48;
  int n = nt * 16 + (lane & 15);
  int k = kc * 32 + ((lane >> 4) << 3) + jj;
  const float* w = d ? wb : wf;
  oB[idx] = f2bf(w[n * 256 + k]);
}

// Whh -> bf16 MFMA A-frags (R4 layout).
// pA[dir][tile(48)][kc(8)][lane(64)][jj(8)]: row = tile*16 + (lane&15),
// k = kc*32 + (lane>>4)*8 + jj.
__global__ __launch_bounds__(256) void prep_packA(
    const float* __restrict__ wf, const float* __restrict__ wb,
    unsigned short* __restrict__ oA) {
  int idx = blockIdx.x * 256 + threadIdx.x;      // 0 .. 2*196608-1
  int d = idx >= 196608;
  int o = idx - d * 196608;
  int jj   = o & 7;
  int lane = (o >> 3) & 63;
  int kc   = (o >> 9) & 7;
  int tl   = o >> 12;                            // 0..47
  int row  = tl * 16 + (lane & 15);
  int k    = kc * 32 + ((lane >> 4) << 3) + jj;
  const float* w = d ? wb : wf;
  oA[idx] = f2bf(w[row * 256 + k]);
}

// ---------------- fused launch: scan(chunk c) + xg_gemm(chunk c+1) --------
// Blocks [0, nscan): recurrent scan, 512 thr (R4 structure, s_setprio(1)).
// Blocks [nscan, nscan+2*Tc): xg GEMM for the next chunk, 512 thr / 8 waves
// (wave w: m-tile w&3, n-tiles [24*(w>>2), 24*(w>>2)+24)), B staged in LDS.
__global__ __launch_bounds__(512, 2) void fused_step(
    const int* __restrict__ seq, const int* __restrict__ lens,
    const unsigned short* __restrict__ embB,
    const unsigned short* __restrict__ pWihB,
    const unsigned short* __restrict__ pA,
    const float* __restrict__ bih_f, const float* __restrict__ bih_b,
    const float* __restrict__ bhh_f, const float* __restrict__ bhh_b,
    float* __restrict__ out, float* __restrict__ hcar,
    const float* __restrict__ xs_f, const float* __restrict__ xs_b,  // scan reads
    float* __restrict__ xw_f, float* __restrict__ xw_b,              // xg writes
    int nscan, int s_base_f, int s_base_b, int Tc, int is_last, int do_add,
    int xg_on, int x_base_f, int x_base_b) {
  __shared__ __align__(16) unsigned char smem[49152];
  const int bid = (int)blockIdx.x;
  const int tid = threadIdx.x;
  const int lane = tid & 63;

  if (bid < nscan) {
    // ---------------- recurrent scan (R4 known-good structure) ----------
    __builtin_amdgcn_s_setprio(1);               // favor scan over co-resident xg
    const int wv  = tid >> 6;                    // 0..7
    const int qp  = bid >> 1;                    // batch pair
    const int dir = bid & 1;
    const int b0  = qp * 2;

    const float* xg  = dir ? xs_b : xs_f;
    const float* bhh = dir ? bhh_b : bhh_f;
    const int len0 = lens[b0], len1 = lens[b0 + 1];
    const int lenmax = len0 > len1 ? len0 : len1;
    const int base = dir ? s_base_b : s_base_f;

    // Resident A-fragments: 6 tiles x 8 k-chunks x 4 VGPRs = 192 regs.
    short8 af[6][8];
    {
      const short8* pA8 = (const short8*)(pA + (size_t)dir * 196608);
#pragma unroll
      for (int i = 0; i < 6; ++i)
#pragma unroll
        for (int kc = 0; kc < 8; ++kc)
          af[i][kc] = pA8[(((wv * 6 + i) * 8 + kc) << 6) + lane];
    }

    unsigned short* hbf = (unsigned short*)smem;        // 2*288 ush (stride 288)
    float*          res = (float*)(smem + 1280);        // 2*784 fl  (stride 784)

    // Epilogue role: thread = (b = tid>>8, j = tid&255); h fp32 lives here.
    const int b  = tid >> 8;
    const int j  = tid & 255;
    const int bb = b0 + b;
    const int blen = b ? len1 : len0;
    float hreg = hcar[dir * 16384 + bb * 256 + j];
    const float bhn = bhh[512 + j];                     // r,z biases folded in xg
    hbf[b * 288 + j] = f2bf(hreg);
    __syncthreads();

    int s_lo, s_hi;
    if (dir == 0) { s_lo = 0; int e = lenmax - base; s_hi = e < 0 ? 0 : (e > Tc ? Tc : e); }
    else { int sk = base + Tc - lenmax; s_lo = sk < 0 ? 0 : (sk > Tc ? Tc : sk); s_hi = Tc; }

    const int nB = lane & 15, qq = lane >> 4;
    const bool bld = nB < 2;                            // 8 lanes/wave carry B data
    const unsigned short* hsrc = &hbf[nB * 288 + qq * 8];

    // Preload first step's epilogue operands (all 512 threads, coalesced).
    float xr = 0.f, xz = 0.f, xn = 0.f, oprev = 0.f;
    if (s_lo < s_hi) {
      const int t0  = dir ? (base + (Tc - 1 - s_lo)) : (base + s_lo);
      const float* xrow = xg + ((size_t)(t0 - base) * 64 + bb) * 768 + j;
      xr = xrow[0]; xz = xrow[256]; xn = xrow[512];
      if (do_add) oprev = out[((size_t)t0 * 64 + bb) * 256 + j];
    }

    for (int s = s_lo; s < s_hi; ++s) {
      const int t  = dir ? (base + (Tc - 1 - s)) : (base + s);
      const bool act = t < blen;

      // Prefetch NEXT step's operands; consumed next iteration.
      const int sn = (s + 1 < s_hi) ? s + 1 : s;
      const int tn = dir ? (base + (Tc - 1 - sn)) : (base + sn);
      float xr2, xz2, xn2, oprev2 = 0.f;
      {
        const float* xrow = xg + ((size_t)(tn - base) * 64 + bb) * 768 + j;
        xr2 = xrow[0]; xz2 = xrow[256]; xn2 = xrow[512];
        if (do_add) oprev2 = out[((size_t)tn * 64 + bb) * 256 + j];
      }

      floatx4 acc[6];
#pragma unroll
      for (int i = 0; i < 6; ++i) acc[i] = (floatx4){0.f, 0.f, 0.f, 0.f};

#pragma unroll
      for (int kc = 0; kc < 8; ++kc) {
        short8 bfr = {0, 0, 0, 0, 0, 0, 0, 0};
        if (bld) bfr = *(const short8*)(hsrc + kc * 32);  // conflict-free masked b128
#pragma unroll
        for (int i = 0; i < 6; ++i)
          acc[i] = __builtin_amdgcn_mfma_f32_16x16x32_bf16(af[i][kc], bfr, acc[i], 0, 0, 0);
      }

      // extract: D col = lane&15 (batch), row = (lane>>4)*4 + reg
      if (bld) {
#pragma unroll
        for (int i = 0; i < 6; ++i) {
          int r0 = (wv * 6 + i) * 16 + qq * 4;
          *(floatx4*)&res[nB * 784 + r0] = acc[i];
        }
      }
      __syncthreads();

      // epilogue: all 512 threads, one cell each
      float ar = res[b * 784 + j];
      float az = res[b * 784 + 256 + j];
      float an = res[b * 784 + 512 + j];
      float r  = sigmoid_(xr + ar);                     // bhr folded into xg
      float z  = sigmoid_(xz + az);                     // bhz folded into xg
      float nn = tanh_(xn + r * (an + bhn));
      float hn = (1.0f - z) * nn + z * hreg;
      if (act) {
        hreg = hn;
        hbf[b * 288 + j] = f2bf(hn);
        out[((size_t)t * 64 + bb) * 256 + j] = do_add ? (oprev + hn) : hn;
      }
      __syncthreads();                                  // hbf/res consistent

      xr = xr2; xz = xz2; xn = xn2; oprev = oprev2;
    }

    hcar[dir * 16384 + bb * 256 + j] = hreg;
    if (is_last)
      out[(size_t)1024 * 64 * 256 + (size_t)dir * 16384 + bb * 256 + j] = hreg;

  } else if (xg_on) {
    // ---------------- xg GEMM for the NEXT chunk (8 waves) --------------
    const int idx  = bid - nscan;                // 0 .. 2*Tc-1
    const int sx   = idx >> 1;
    const int dir  = idx & 1;
    const int w    = tid >> 6;                   // 0..7
    const int mt   = w & 3;                      // m-tile (batch group)
    const int h2   = w >> 2;                     // n-half
    const int t    = (dir ? x_base_b : x_base_f) + sx;
    const int c    = lane & 15, qq = lane >> 4;

    const float* bih = dir ? bih_b : bih_f;
    const float* bhh = dir ? bhh_b : bhh_f;
    float* xgo = (dir ? xw_b : xw_f) + (size_t)sx * 64 * 768;

    // A-frags: token row for m = lane&15 of m-tile mt; prefetch all 8 kc.
    const int tk = seq[t * 64 + mt * 16 + c];
    const unsigned short* aptr = embB + (size_t)tk * 256 + qq * 8;
    short8 afr[8];
#pragma unroll
    for (int kc = 0; kc < 8; ++kc) afr[kc] = *(const short8*)(aptr + kc * 32);

    float4* Bs4 = (float4*)smem;                 // 3072 float4 = 48 KB

    floatx4 acc[24];
#pragma unroll
    for (int q = 0; q < 24; ++q) acc[q] = (floatx4){0.f, 0.f, 0.f, 0.f};

    for (int kc = 0; kc < 8; ++kc) {
      __syncthreads();
      const float4* src = (const float4*)(pWihB + (size_t)dir * 196608 + kc * 24576);
#pragma unroll
      for (int i = 0; i < 6; ++i) Bs4[tid + i * 512] = src[tid + i * 512];
      __syncthreads();
      const short8* bsv = (const short8*)Bs4;
      short8 af = afr[kc];
#pragma unroll
      for (int q = 0; q < 24; ++q) {
        int nt = h2 * 24 + q;
        acc[q] = __builtin_amdgcn_mfma_f32_16x16x32_bf16(af, bsv[nt * 64 + lane], acc[q], 0, 0, 0);
      }
    }

    // D: col = lane&15 (n within tile), row = qq*4+reg (m = batch in tile).
    // Bias: bih everywhere + bhh folded for the r,z gates (n < 512).
#pragma unroll
    for (int q = 0; q < 24; ++q) {
      int n = (h2 * 24 + q) * 16 + c;
      float bv = bih[n] + (n < 512 ? bhh[n] : 0.0f);
#pragma unroll
      for (int r = 0; r < 4; ++r)
        xgo[(size_t)(mt * 16 + qq * 4 + r) * 768 + n] = acc[q][r] + bv;
    }
  }
}

extern "C" void kernel_launch(void* const* d_in, const int* in_sizes, int n_in,
                              void* d_out, int out_size, void* d_ws, size_t ws_size,
                              hipStream_t stream) {
  const int*   seq   = (const int*)d_in[0];
  const int*   lens  = (const int*)d_in[1];
  const float* emb   = (const float*)d_in[2];
  const float* Wih_f = (const float*)d_in[3];
  const float* Whh_f = (const float*)d_in[4];
  const float* bih_f = (const float*)d_in[5];
  const float* bhh_f = (const float*)d_in[6];
  const float* Wih_b = (const float*)d_in[7];
  const float* Whh_b = (const float*)d_in[8];
  const float* bih_b = (const float*)d_in[9];
  const float* bhh_b = (const float*)d_in[10];
  float* out = (float*)d_out;
  float* ws  = (float*)d_ws;

  float*          hcar   = ws;
  unsigned short* pA     = (unsigned short*)(ws + 32768);
  unsigned short* pWihB  = (unsigned short*)(ws + 229376);
  unsigned short* embB   = (unsigned short*)(ws + 425984);
  float*          xgbase = ws + 4521984;

  // Largest Tc whose FOUR xg chunk buffers ([parity][dir]) fit in ws.
  int Tc = 8;
  const int cands[7] = {512, 256, 128, 64, 32, 16, 8};
  for (int i = 0; i < 7; ++i) {
    size_t need = (4521984ull + 4ull * (size_t)cands[i] * 49152ull) * 4ull;
    if (need <= ws_size) { Tc = cands[i]; break; }
  }
  const int C = 1024 / Tc;
  float* xb[2][2];                               // [parity][dir]
  for (int p = 0; p < 2; ++p)
    for (int d = 0; d < 2; ++d)
      xb[p][d] = xgbase + ((size_t)(p * 2 + d)) * Tc * 49152;

  hipMemsetAsync(d_out, 0, (size_t)1024 * 64 * 256 * 4, stream);  // masked outputs stay 0
  hipMemsetAsync(hcar, 0, 32768ull * 4ull, stream);               // initial h = 0
  prep_embB<<<dim3(8000), dim3(256), 0, stream>>>(emb, embB);
  prep_packB<<<dim3(1536), dim3(256), 0, stream>>>(Wih_f, Wih_b, pWihB);
  prep_packA<<<dim3(1536), dim3(256), 0, stream>>>(Whh_f, Whh_b, pA);

  // Prologue: xg for chunk 0 only (parity 0).
  fused_step<<<dim3(2 * Tc), dim3(512), 0, stream>>>(
      seq, lens, embB, pWihB, pA, bih_f, bih_b, bhh_f, bhh_b, out, hcar,
      xb[0][0], xb[0][1], xb[0][0], xb[0][1],
      /*nscan=*/0, 0, 0, Tc, 0, 0, /*xg_on=*/1, /*x_base_f=*/0, /*x_base_b=*/(C - 1) * Tc);

  // Pipeline: launch c runs scan(chunk c) on blocks [0,64) and xg(chunk c+1)
  // on blocks [64, 64+2*Tc). Kernel boundaries provide the ordering.
  for (int c = 0; c < C; ++c) {
    int xgon = (c + 1 < C) ? 1 : 0;
    int nblk = 64 + (xgon ? 2 * Tc : 0);
    fused_step<<<dim3(nblk), dim3(512), 0, stream>>>(
        seq, lens, embB, pWihB, pA, bih_f, bih_b, bhh_f, bhh_b, out, hcar,
        xb[c & 1][0], xb[c & 1][1], xb[(c + 1) & 1][0], xb[(c + 1) & 1][1],
        /*nscan=*/64, /*s_base_f=*/c * Tc, /*s_base_b=*/(C - 1 - c) * Tc, Tc,
        /*is_last=*/(c == C - 1) ? 1 : 0, /*do_add=*/(2 * c >= C) ? 1 : 0,
        xgon, /*x_base_f=*/(c + 1) * Tc, /*x_base_b=*/(C - 2 - c) * Tc);
  }
}